// Round 6
// baseline (205.841 us; speedup 1.0000x reference)
//
#include <hip/hip_runtime.h>
#include <math.h>

#define NB 32768
#define NC 1000
#define ND 512
#define NTILES 63          // 63*16 = 1008 >= 1000 class columns
#define LOG2E 1.4426950408889634f
#define LN2 0.6931471805599453f
#define S2 14.426950408889634f   // (1/T) * log2(e)
#define NBUCKET 64

typedef __attribute__((ext_vector_type(8))) short short8;
typedef __attribute__((ext_vector_type(4))) float f32x4;

__device__ __forceinline__ float fexp2(float x) {
    float r; asm("v_exp_f32 %0, %1" : "=v"(r) : "v"(x)); return r;
}
__device__ __forceinline__ float flog2(float x) {
    float r; asm("v_log_f32 %0, %1" : "=v"(r) : "v"(x)); return r;
}
__device__ __forceinline__ unsigned short bf16_rne(float f) {
    unsigned int u = __builtin_bit_cast(unsigned int, f);
    u += 0x7FFFu + ((u >> 16) & 1u);
    return (unsigned short)(u >> 16);
}
__device__ __forceinline__ short8 pack8f(float4 a, float4 b) {
    short8 s;
    s[0] = (short)bf16_rne(a.x); s[1] = (short)bf16_rne(a.y);
    s[2] = (short)bf16_rne(a.z); s[3] = (short)bf16_rne(a.w);
    s[4] = (short)bf16_rne(b.x); s[5] = (short)bf16_rne(b.y);
    s[6] = (short)bf16_rne(b.z); s[7] = (short)bf16_rne(b.w);
    return s;
}

// ---------------- normalize prototypes -> bf16 in MFMA FRAGMENT ORDER ----------------
// frag[tile*1024 + kk*64 + g*16 + r] (short8 units) = row (tile*16+r), cols 32*kk+8*g..+8.
// A wave's A-operand load for (tile,kk) is frag[tile*1024+kk*64+lane]: 1KB contiguous.
__global__ __launch_bounds__(256) void norm_protos(const float* __restrict__ pro,
                                                   unsigned short* __restrict__ pbf) {
    const int row = blockIdx.x, t = threadIdx.x;   // grid 1024 rows (>=NC padded w/ zeros)
    const int tile = row >> 4, r = row & 15;
    const int kk = t >> 4, g = (t >> 2) & 3, slot = t & 3;
    unsigned int* dst = (unsigned int*)pbf +
        ((size_t)tile * 1024 + kk * 64 + g * 16 + r) * 4 + slot;
    if (row >= NC) { *dst = 0u; return; }  // zero pad rows (uniform per block)
    const float* rp = pro + (size_t)row * ND;
    const float x0 = rp[2 * t], x1 = rp[2 * t + 1];
    float ss = x0 * x0 + x1 * x1;
#pragma unroll
    for (int o = 1; o < 64; o <<= 1) ss += __shfl_xor(ss, o, 64);
    __shared__ float part[4];
    if ((t & 63) == 0) part[t >> 6] = ss;
    __syncthreads();
    const float nrm = sqrtf(part[0] + part[1] + part[2] + part[3]);
    const float sc = 1.0f / fmaxf(nrm, 1e-12f);
    *dst = (unsigned int)bf16_rne(x0 * sc) | ((unsigned int)bf16_rne(x1 * sc) << 16);
}

// ---------------- fused simloss + cross-entropy, 16 rows/wave, 2 waves/SIMD ----------------
// Sim: 16x16x32 MFMA swapped operands, D layout (m89): col=lane&15=feature row,
// class=(lane>>4)*4+reg. P half-tiles (8 kk) double-buffered in registers from L1/L2.
__global__ __launch_bounds__(256, 2) void main_kernel(const float* __restrict__ feat,
                                                      const float* __restrict__ logits,
                                                      const int* __restrict__ labels,
                                                      const unsigned short* __restrict__ pbf,
                                                      float* __restrict__ buckets) {
    __shared__ float wsum[4], wsumce[4];
    const int t = threadIdx.x;
    const int wid = t >> 6, lane = t & 63;
    const int r16 = lane & 15, g = lane >> 4;
    const int rowbase = blockIdx.x * 64 + wid * 16;
    const short8* frag = (const short8*)pbf;

    // P half-tile 0 (tile 0, kk 0..7) into registers first: overlaps feature-load latency
    short8 PA[8], PB[8];
#pragma unroll
    for (int k = 0; k < 8; ++k) PA[k] = frag[k * 64 + lane];

    // Feature fragments: bf[kk] = feat[row][32*kk + 8*g .. +8]
    short8 bf[16];
    {
        const float* f0 = feat + (size_t)(rowbase + r16) * ND + 8 * g;
#pragma unroll
        for (int kk = 0; kk < 16; ++kk)
            bf[kk] = pack8f(*(const float4*)(f0 + 32 * kk), *(const float4*)(f0 + 32 * kk + 4));
    }
    int lab0 = labels[rowbase + r16];
    lab0 = lab0 < 0 ? 0 : (lab0 > NC - 1 ? NC - 1 : lab0);

    float m0 = -INFINITY, ls0 = 0.f, lv0 = 0.f;

#pragma unroll 1
    for (int ct = 0; ct < NTILES; ++ct) {
        const int base = ct * 1024;
        // load odd half (kk 8..15) of this tile while computing even half
#pragma unroll
        for (int k = 0; k < 8; ++k) PB[k] = frag[base + (8 + k) * 64 + lane];
        f32x4 aE = {0.f, 0.f, 0.f, 0.f};
#pragma unroll
        for (int k = 0; k < 8; ++k)
            aE = __builtin_amdgcn_mfma_f32_16x16x32_bf16(PA[k], bf[k], aE, 0, 0, 0);
        // prefetch next tile's even half while computing odd half
        const int nbase = (ct < NTILES - 1) ? base + 1024 : base;
#pragma unroll
        for (int k = 0; k < 8; ++k) PA[k] = frag[nbase + k * 64 + lane];
        f32x4 aO = {0.f, 0.f, 0.f, 0.f};
#pragma unroll
        for (int k = 0; k < 8; ++k)
            aO = __builtin_amdgcn_mfma_f32_16x16x32_bf16(PB[k], bf[8 + k], aO, 0, 0, 0);

        const int cbase = ct * 16 + g * 4;
        float x[4];
#pragma unroll
        for (int rI = 0; rI < 4; ++rI) {
            const float v = (aE[rI] + aO[rI]) * S2;
            x[rI] = (cbase + rI < NC) ? v : -INFINITY;   // only bites at ct==62
            lv0 += (cbase + rI == lab0) ? v : 0.f;
        }
        const float tmax = fmaxf(fmaxf(x[0], x[1]), fmaxf(x[2], x[3]));
        const float mn = fmaxf(m0, tmax);
        ls0 *= fexp2(m0 - mn);  // =1 if no new max; =0 on first tile
        m0 = mn;
        ls0 += fexp2(x[0] - mn) + fexp2(x[1] - mn) + fexp2(x[2] - mn) + fexp2(x[3] - mn);
    }

    // Merge the 4 lane-groups (g=0..3) holding the same feature rows
#pragma unroll
    for (int o = 16; o <= 32; o <<= 1) {
        const float mo = __shfl_xor(m0, o, 64), lo = __shfl_xor(ls0, o, 64);
        lv0 += __shfl_xor(lv0, o, 64);
        const float mm = fmaxf(m0, mo);
        ls0 = ls0 * fexp2(m0 - mm) + lo * fexp2(mo - mm);
        m0 = mm;
    }
    const float row0 = (m0 + flog2(ls0) - lv0) * LN2;  // replicated on 4 lanes
    float mine = row0 * (1.0f / (4.0f * (float)NB));
#pragma unroll
    for (int o = 1; o < 64; o <<= 1) mine += __shfl_xor(mine, o, 64);

    // ---- CE phase: this wave's 16 rows of logits, 2 rows in flight for ILP ----
    float localce = 0.f;
#pragma unroll 1
    for (int i = 0; i < 16; i += 2) {
        const float* rpA = logits + (size_t)(rowbase + i) * NC;
        const float* rpB = rpA + NC;
        float xa[16], xb[16];
#pragma unroll
        for (int j = 0; j < 4; ++j) {
            const int c0 = lane * 4 + j * 256;
            if (c0 < NC) {
                const float4 va = *(const float4*)(rpA + c0);
                const float4 vb = *(const float4*)(rpB + c0);
                xa[4 * j] = va.x * LOG2E; xa[4 * j + 1] = va.y * LOG2E;
                xa[4 * j + 2] = va.z * LOG2E; xa[4 * j + 3] = va.w * LOG2E;
                xb[4 * j] = vb.x * LOG2E; xb[4 * j + 1] = vb.y * LOG2E;
                xb[4 * j + 2] = vb.z * LOG2E; xb[4 * j + 3] = vb.w * LOG2E;
            } else {
                xa[4 * j] = xa[4 * j + 1] = xa[4 * j + 2] = xa[4 * j + 3] = -INFINITY;
                xb[4 * j] = xb[4 * j + 1] = xb[4 * j + 2] = xb[4 * j + 3] = -INFINITY;
            }
        }
        float mA = -INFINITY, mB = -INFINITY;
#pragma unroll
        for (int i2 = 0; i2 < 16; ++i2) { mA = fmaxf(mA, xa[i2]); mB = fmaxf(mB, xb[i2]); }
#pragma unroll
        for (int o = 1; o < 64; o <<= 1) {   // two independent chains interleave
            mA = fmaxf(mA, __shfl_xor(mA, o, 64));
            mB = fmaxf(mB, __shfl_xor(mB, o, 64));
        }
        float sA = 0.f, sB = 0.f;
#pragma unroll
        for (int i2 = 0; i2 < 16; ++i2) { sA += fexp2(xa[i2] - mA); sB += fexp2(xb[i2] - mB); }
#pragma unroll
        for (int o = 1; o < 64; o <<= 1) {
            sA += __shfl_xor(sA, o, 64);
            sB += __shfl_xor(sB, o, 64);
        }
        int labA = labels[rowbase + i], labB = labels[rowbase + i + 1];
        labA = labA < 0 ? 0 : (labA > NC - 1 ? NC - 1 : labA);
        labB = labB < 0 ? 0 : (labB > NC - 1 ? NC - 1 : labB);
        localce += (mA + flog2(sA)) * LN2 - rpA[labA];
        localce += (mB + flog2(sB)) * LN2 - rpB[labB];
    }

    if (lane == 0) { wsum[wid] = mine; wsumce[wid] = localce; }
    __syncthreads();
    if (t == 0) {
        const int b = (blockIdx.x & (NBUCKET - 1)) * 16;
        atomicAdd(buckets + b, wsum[0] + wsum[1] + wsum[2] + wsum[3]);
        atomicAdd(buckets + 1024 + b,
                  (wsumce[0] + wsumce[1] + wsumce[2] + wsumce[3]) * (1.0f / (float)NB));
    }
}

// ---------------- prototype Gram exp-sum (off-diagonal); frag-layout reads ----------------
__global__ __launch_bounds__(256) void gram_kernel(const unsigned short* __restrict__ pbf,
                                                   float* __restrict__ buckets) {
    __shared__ float wsum[4];
    const int t = threadIdx.x;
    const int wid = t >> 6, lane = t & 63;
    const int r16 = lane & 15, g = lane >> 4;
    const int ct = blockIdx.y;                    // class tile 0..62 (A side)
    const int btile = blockIdx.x * 4 + wid;       // feature-side tile 0..63 (pad zeros)
    const int irow = btile * 16 + r16;
    const short8* frag = (const short8*)pbf;

    short8 af[16], bfr[16];
#pragma unroll
    for (int kk = 0; kk < 16; ++kk) {
        af[kk] = frag[(size_t)ct * 1024 + kk * 64 + lane];
        bfr[kk] = frag[(size_t)btile * 1024 + kk * 64 + lane];
    }
    f32x4 dacc = {0.f, 0.f, 0.f, 0.f};
#pragma unroll
    for (int kk = 0; kk < 16; ++kk)
        dacc = __builtin_amdgcn_mfma_f32_16x16x32_bf16(af[kk], bfr[kk], dacc, 0, 0, 0);

    float s = 0.f;
    if (irow < NC) {
        const int cbase = ct * 16 + g * 4;
#pragma unroll
        for (int rI = 0; rI < 4; ++rI) {
            const int j = cbase + rI;
            if (j < NC && j != irow) s += fexp2(dacc[rI] * LOG2E);
        }
    }
#pragma unroll
    for (int o = 1; o < 64; o <<= 1) s += __shfl_xor(s, o, 64);
    if (lane == 0) wsum[wid] = s;
    __syncthreads();
    if (t == 0)
        atomicAdd(buckets + ((blockIdx.x + 16 * blockIdx.y) & (NBUCKET - 1)) * 16,
                  wsum[0] + wsum[1] + wsum[2] + wsum[3]);
}

// ---------------- final combine: sum buckets ----------------
__global__ void combine_kernel(const float* __restrict__ a, float* __restrict__ out) {
    const int t = threadIdx.x;  // 64 threads
    float s = a[t * 16], c = a[1024 + t * 16], gr = a[2048 + t * 16];
#pragma unroll
    for (int o = 1; o < 64; o <<= 1) {
        s += __shfl_xor(s, o, 64);
        c += __shfl_xor(c, o, 64);
        gr += __shfl_xor(gr, o, 64);
    }
    if (t == 0) out[0] = s + c + logf(gr) * (1.0f / (float)NC);
}

extern "C" void kernel_launch(void* const* d_in, const int* in_sizes, int n_in,
                              void* d_out, int out_size, void* d_ws, size_t ws_size,
                              hipStream_t stream) {
    const float* feat   = (const float*)d_in[0];  // [32768,512]
    const float* logits = (const float*)d_in[1];  // [32768,1000]
    const int*   labels = (const int*)d_in[2];    // [32768]
    const float* pro    = (const float*)d_in[3];  // [1000,512]
    float* out = (float*)d_out;

    float* acc = (float*)d_ws;  // buckets: [0]=sim, [1024]=ce, [2048]=gram (stride-16 floats)
    unsigned short* pbf = (unsigned short*)((char*)d_ws + 16384);  // frag-order bf16, 1 MiB

    hipMemsetAsync(d_ws, 0, 3072 * sizeof(float), stream);
    hipLaunchKernelGGL(norm_protos,    dim3(1024),    dim3(256), 0, stream, pro, pbf);
    hipLaunchKernelGGL(main_kernel,    dim3(NB / 64), dim3(256), 0, stream, feat, logits, labels, pbf, acc);
    hipLaunchKernelGGL(gram_kernel,    dim3(16, 63),  dim3(256), 0, stream, pbf, acc + 2048);
    hipLaunchKernelGGL(combine_kernel, dim3(1),       dim3(64),  0, stream, acc, out);
}

// Round 7
// 94.893 us; speedup vs baseline: 2.1692x; 2.1692x over previous
//
#include <hip/hip_runtime.h>
#include <math.h>

#define NB 32768
#define NC 1000
#define ND 512
#define NTILES 63          // 63*16 = 1008 >= 1000 class columns
#define LOG2E 1.4426950408889634f
#define LN2 0.6931471805599453f
#define S2 14.426950408889634f   // (1/T) * log2(e)
#define NBUCKET 64

typedef __attribute__((ext_vector_type(8))) short short8;
typedef __attribute__((ext_vector_type(4))) float f32x4;

__device__ __forceinline__ float fexp2(float x) {
    float r; asm("v_exp_f32 %0, %1" : "=v"(r) : "v"(x)); return r;
}
__device__ __forceinline__ float flog2(float x) {
    float r; asm("v_log_f32 %0, %1" : "=v"(r) : "v"(x)); return r;
}
__device__ __forceinline__ unsigned short bf16_rne(float f) {
    unsigned int u = __builtin_bit_cast(unsigned int, f);
    u += 0x7FFFu + ((u >> 16) & 1u);
    return (unsigned short)(u >> 16);
}
__device__ __forceinline__ short8 pack8f(float4 a, float4 b) {
    short8 s;
    s[0] = (short)bf16_rne(a.x); s[1] = (short)bf16_rne(a.y);
    s[2] = (short)bf16_rne(a.z); s[3] = (short)bf16_rne(a.w);
    s[4] = (short)bf16_rne(b.x); s[5] = (short)bf16_rne(b.y);
    s[6] = (short)bf16_rne(b.z); s[7] = (short)bf16_rne(b.w);
    return s;
}

// ---------------- normalize prototypes -> bf16 in MFMA FRAGMENT ORDER ----------------
// frag[tile*1024 + kk*64 + g*16 + r] (short8 units) = row (tile*16+r), cols 32*kk+8*g..+8.
// A wave's A-operand load for (tile,kk) is frag[tile*1024+kk*64+lane]: 1KB contiguous.
__global__ __launch_bounds__(256) void norm_protos(const float* __restrict__ pro,
                                                   unsigned short* __restrict__ pbf) {
    const int row = blockIdx.x, t = threadIdx.x;   // grid 1024 rows (>=NC padded w/ zeros)
    const int tile = row >> 4, r = row & 15;
    const int kk = t >> 4, g = (t >> 2) & 3, slot = t & 3;
    unsigned int* dst = (unsigned int*)pbf +
        ((size_t)tile * 1024 + kk * 64 + g * 16 + r) * 4 + slot;
    if (row >= NC) { *dst = 0u; return; }  // zero pad rows (uniform per block)
    const float* rp = pro + (size_t)row * ND;
    const float x0 = rp[2 * t], x1 = rp[2 * t + 1];
    float ss = x0 * x0 + x1 * x1;
#pragma unroll
    for (int o = 1; o < 64; o <<= 1) ss += __shfl_xor(ss, o, 64);
    __shared__ float part[4];
    if ((t & 63) == 0) part[t >> 6] = ss;
    __syncthreads();
    const float nrm = sqrtf(part[0] + part[1] + part[2] + part[3]);
    const float sc = 1.0f / fmaxf(nrm, 1e-12f);
    *dst = (unsigned int)bf16_rne(x0 * sc) | ((unsigned int)bf16_rne(x1 * sc) << 16);
}

// ---------------- fused simloss + cross-entropy ----------------
// Sim: 16x16x32 MFMA swapped operands, D layout (m89): col=lane&15=feature row,
// class=(lane>>4)*4+reg. Wave holds 32 feature rows; P tiles double-buffered in
// REGISTERS straight from L1/L2; per-tile-pair barrier locksteps 4 waves for L1 reuse.
#define TILE_BODY(P, CT)                                                            \
    do {                                                                            \
        f32x4 a0 = {0.f, 0.f, 0.f, 0.f}, a1 = {0.f, 0.f, 0.f, 0.f};                \
        _Pragma("unroll")                                                           \
        for (int kk = 0; kk < 16; ++kk) {                                           \
            a0 = __builtin_amdgcn_mfma_f32_16x16x32_bf16(P[kk], bf0[kk], a0, 0, 0, 0); \
            a1 = __builtin_amdgcn_mfma_f32_16x16x32_bf16(P[kk], bf1[kk], a1, 0, 0, 0); \
        }                                                                           \
        const int cbase = (CT) * 16 + g * 4;                                        \
        {                                                                           \
            float x[4];                                                            \
            _Pragma("unroll")                                                       \
            for (int rI = 0; rI < 4; ++rI) {                                        \
                const float v = a0[rI] * S2;                                        \
                x[rI] = (cbase + rI < NC) ? v : -INFINITY;                          \
                lv0 += (cbase + rI == lab0) ? v : 0.f;                              \
            }                                                                       \
            const float tmax = fmaxf(fmaxf(x[0], x[1]), fmaxf(x[2], x[3]));         \
            const float mn = fmaxf(m0, tmax);                                       \
            ls0 *= fexp2(m0 - mn);                                                  \
            m0 = mn;                                                                \
            ls0 += fexp2(x[0] - mn) + fexp2(x[1] - mn) + fexp2(x[2] - mn) + fexp2(x[3] - mn); \
        }                                                                           \
        {                                                                           \
            float x[4];                                                            \
            _Pragma("unroll")                                                       \
            for (int rI = 0; rI < 4; ++rI) {                                        \
                const float v = a1[rI] * S2;                                        \
                x[rI] = (cbase + rI < NC) ? v : -INFINITY;                          \
                lv1 += (cbase + rI == lab1) ? v : 0.f;                              \
            }                                                                       \
            const float tmax = fmaxf(fmaxf(x[0], x[1]), fmaxf(x[2], x[3]));         \
            const float mn = fmaxf(m1, tmax);                                       \
            ls1 *= fexp2(m1 - mn);                                                  \
            m1 = mn;                                                                \
            ls1 += fexp2(x[0] - mn) + fexp2(x[1] - mn) + fexp2(x[2] - mn) + fexp2(x[3] - mn); \
        }                                                                           \
    } while (0)

__global__ __launch_bounds__(256, 1) void main_kernel(const float* __restrict__ feat,
                                                      const float* __restrict__ logits,
                                                      const int* __restrict__ labels,
                                                      const unsigned short* __restrict__ pbf,
                                                      float* __restrict__ buckets) {
    __shared__ float wsum[4], wsumce[4];
    const int t = threadIdx.x;
    const int wid = t >> 6, lane = t & 63;
    const int r16 = lane & 15, g = lane >> 4;
    const int rowbase = blockIdx.x * 128 + wid * 32;
    const short8* frag = (const short8*)pbf;

    // P tile 0 into registers (issue first: overlaps feature-load latency)
    short8 PA[16], PB[16];
#pragma unroll
    for (int k = 0; k < 16; ++k) PA[k] = frag[k * 64 + lane];

    // Feature fragments for 2 row-groups: bf*[kk] = feat[row][32*kk + 8*g .. +8]
    short8 bf0[16], bf1[16];
    {
        const float* f0 = feat + (size_t)(rowbase + r16) * ND + 8 * g;
        const float* f1 = f0 + 16 * ND;
#pragma unroll
        for (int kk = 0; kk < 16; ++kk) {
            bf0[kk] = pack8f(*(const float4*)(f0 + 32 * kk), *(const float4*)(f0 + 32 * kk + 4));
            bf1[kk] = pack8f(*(const float4*)(f1 + 32 * kk), *(const float4*)(f1 + 32 * kk + 4));
        }
    }
    int lab0 = labels[rowbase + r16];
    int lab1 = labels[rowbase + 16 + r16];
    lab0 = lab0 < 0 ? 0 : (lab0 > NC - 1 ? NC - 1 : lab0);
    lab1 = lab1 < 0 ? 0 : (lab1 > NC - 1 ? NC - 1 : lab1);

    float m0 = -INFINITY, ls0 = 0.f, lv0 = 0.f;
    float m1 = -INFINITY, ls1 = 0.f, lv1 = 0.f;

    // 63 tiles: 31 double-buffered pairs + tail. Barrier per pair locksteps the
    // block's 4 waves so they share L1 lines of the frag stream.
#pragma unroll 1
    for (int ct = 0; ct < 62; ct += 2) {
#pragma unroll
        for (int k = 0; k < 16; ++k) PB[k] = frag[(ct + 1) * 1024 + k * 64 + lane];
        TILE_BODY(PA, ct);
#pragma unroll
        for (int k = 0; k < 16; ++k) PA[k] = frag[(ct + 2) * 1024 + k * 64 + lane];
        TILE_BODY(PB, ct + 1);
        __syncthreads();
    }
    TILE_BODY(PA, 62);

    // Merge the 4 lane-groups (g=0..3) holding the same feature rows
#pragma unroll
    for (int o = 16; o <= 32; o <<= 1) {
        {
            const float mo = __shfl_xor(m0, o, 64), lo = __shfl_xor(ls0, o, 64);
            lv0 += __shfl_xor(lv0, o, 64);
            const float mm = fmaxf(m0, mo);
            ls0 = ls0 * fexp2(m0 - mm) + lo * fexp2(mo - mm);
            m0 = mm;
        }
        {
            const float mo = __shfl_xor(m1, o, 64), lo = __shfl_xor(ls1, o, 64);
            lv1 += __shfl_xor(lv1, o, 64);
            const float mm = fmaxf(m1, mo);
            ls1 = ls1 * fexp2(m1 - mm) + lo * fexp2(mo - mm);
            m1 = mm;
        }
    }
    const float row0 = (m0 + flog2(ls0) - lv0) * LN2;  // replicated on 4 lanes
    const float row1 = (m1 + flog2(ls1) - lv1) * LN2;
    float mine = (row0 + row1) * (1.0f / (4.0f * (float)NB));
#pragma unroll
    for (int o = 1; o < 64; o <<= 1) mine += __shfl_xor(mine, o, 64);

    // ---- CE phase: 32 rows/wave, 16-lane row-groups, 4 rows in flight ----
    // Lane l16 of quad q handles float4-strip idx = l16 + 16*j (j<16, idx<250)
    // of row rowbase + 4*i + q. Reductions: 4 shfl levels within the quad,
    // 4 independent chains interleaved.
    const int q4 = lane >> 4, l16 = lane & 15;
    float localce = 0.f;
#pragma unroll 1
    for (int i = 0; i < 8; ++i) {
        const int row = rowbase + 4 * i + q4;
        const float* rp = logits + (size_t)row * NC;
        const float4* rp4 = (const float4*)rp;
        float4 xs[16];
#pragma unroll
        for (int j = 0; j < 15; ++j) {
            const float4 v = rp4[l16 + 16 * j];
            xs[j].x = v.x * LOG2E; xs[j].y = v.y * LOG2E;
            xs[j].z = v.z * LOG2E; xs[j].w = v.w * LOG2E;
        }
        if (l16 < 10) {  // idx = l16 + 240 < 250
            const float4 v = rp4[l16 + 240];
            xs[15].x = v.x * LOG2E; xs[15].y = v.y * LOG2E;
            xs[15].z = v.z * LOG2E; xs[15].w = v.w * LOG2E;
        } else {
            xs[15].x = xs[15].y = xs[15].z = xs[15].w = -INFINITY;
        }
        float m = -INFINITY;
#pragma unroll
        for (int j = 0; j < 16; ++j)
            m = fmaxf(m, fmaxf(fmaxf(xs[j].x, xs[j].y), fmaxf(xs[j].z, xs[j].w)));
#pragma unroll
        for (int o = 1; o <= 8; o <<= 1) m = fmaxf(m, __shfl_xor(m, o, 64));
        float s = 0.f;
#pragma unroll
        for (int j = 0; j < 16; ++j)
            s += fexp2(xs[j].x - m) + fexp2(xs[j].y - m) +
                 fexp2(xs[j].z - m) + fexp2(xs[j].w - m);
#pragma unroll
        for (int o = 1; o <= 8; o <<= 1) s += __shfl_xor(s, o, 64);
        if (l16 == 0) {
            int lab = labels[row];
            lab = lab < 0 ? 0 : (lab > NC - 1 ? NC - 1 : lab);
            localce += (m + flog2(s)) * LN2 - rp[lab];
        }
    }

    // localce lives on lanes {0,16,32,48}; full-wave sum
#pragma unroll
    for (int o = 1; o < 64; o <<= 1) localce += __shfl_xor(localce, o, 64);

    if (lane == 0) { wsum[wid] = mine; wsumce[wid] = localce; }
    __syncthreads();
    if (t == 0) {
        const int b = (blockIdx.x & (NBUCKET - 1)) * 16;
        atomicAdd(buckets + b, wsum[0] + wsum[1] + wsum[2] + wsum[3]);
        atomicAdd(buckets + 1024 + b,
                  (wsumce[0] + wsumce[1] + wsumce[2] + wsumce[3]) * (1.0f / (float)NB));
    }
}

// ---------------- prototype Gram exp-sum (off-diagonal); frag-layout reads ----------------
__global__ __launch_bounds__(256) void gram_kernel(const unsigned short* __restrict__ pbf,
                                                   float* __restrict__ buckets) {
    __shared__ float wsum[4];
    const int t = threadIdx.x;
    const int wid = t >> 6, lane = t & 63;
    const int r16 = lane & 15, g = lane >> 4;
    const int ct = blockIdx.y;                    // class tile 0..62 (A side)
    const int btile = blockIdx.x * 4 + wid;       // feature-side tile 0..63 (pad zeros)
    const int irow = btile * 16 + r16;
    const short8* frag = (const short8*)pbf;

    short8 af[16], bfr[16];
#pragma unroll
    for (int kk = 0; kk < 16; ++kk) {
        af[kk] = frag[(size_t)ct * 1024 + kk * 64 + lane];
        bfr[kk] = frag[(size_t)btile * 1024 + kk * 64 + lane];
    }
    f32x4 dacc = {0.f, 0.f, 0.f, 0.f};
#pragma unroll
    for (int kk = 0; kk < 16; ++kk)
        dacc = __builtin_amdgcn_mfma_f32_16x16x32_bf16(af[kk], bfr[kk], dacc, 0, 0, 0);

    float s = 0.f;
    if (irow < NC) {
        const int cbase = ct * 16 + g * 4;
#pragma unroll
        for (int rI = 0; rI < 4; ++rI) {
            const int j = cbase + rI;
            if (j < NC && j != irow) s += fexp2(dacc[rI] * LOG2E);
        }
    }
#pragma unroll
    for (int o = 1; o < 64; o <<= 1) s += __shfl_xor(s, o, 64);
    if (lane == 0) wsum[wid] = s;
    __syncthreads();
    if (t == 0)
        atomicAdd(buckets + ((blockIdx.x + 16 * blockIdx.y) & (NBUCKET - 1)) * 16,
                  wsum[0] + wsum[1] + wsum[2] + wsum[3]);
}

// ---------------- final combine: sum buckets ----------------
__global__ void combine_kernel(const float* __restrict__ a, float* __restrict__ out) {
    const int t = threadIdx.x;  // 64 threads
    float s = a[t * 16], c = a[1024 + t * 16], gr = a[2048 + t * 16];
#pragma unroll
    for (int o = 1; o < 64; o <<= 1) {
        s += __shfl_xor(s, o, 64);
        c += __shfl_xor(c, o, 64);
        gr += __shfl_xor(gr, o, 64);
    }
    if (t == 0) out[0] = s + c + logf(gr) * (1.0f / (float)NC);
}

extern "C" void kernel_launch(void* const* d_in, const int* in_sizes, int n_in,
                              void* d_out, int out_size, void* d_ws, size_t ws_size,
                              hipStream_t stream) {
    const float* feat   = (const float*)d_in[0];  // [32768,512]
    const float* logits = (const float*)d_in[1];  // [32768,1000]
    const int*   labels = (const int*)d_in[2];    // [32768]
    const float* pro    = (const float*)d_in[3];  // [1000,512]
    float* out = (float*)d_out;

    float* acc = (float*)d_ws;  // buckets: [0]=sim, [1024]=ce, [2048]=gram (stride-16 floats)
    unsigned short* pbf = (unsigned short*)((char*)d_ws + 16384);  // frag-order bf16, 1 MiB

    hipMemsetAsync(d_ws, 0, 3072 * sizeof(float), stream);
    hipLaunchKernelGGL(norm_protos,    dim3(1024),     dim3(256), 0, stream, pro, pbf);
    hipLaunchKernelGGL(main_kernel,    dim3(NB / 128), dim3(256), 0, stream, feat, logits, labels, pbf, acc);
    hipLaunchKernelGGL(gram_kernel,    dim3(16, 63),   dim3(256), 0, stream, pbf, acc + 2048);
    hipLaunchKernelGGL(combine_kernel, dim3(1),        dim3(64),  0, stream, acc, out);
}